// Round 13
// baseline (67.527 us; speedup 1.0000x reference)
//
#include <hip/hip_runtime.h>

typedef __attribute__((ext_vector_type(8))) short bf16x8;
typedef __attribute__((ext_vector_type(4))) float f32x4;

#define GAMMA_ 0.5f
#define LOG2E_ 1.4426950408889634f

constexpr int D      = 256;   // feature dim (K)
constexpr int BM     = 64;    // rows of X per block
constexpr int BN     = 64;    // X_train cols per j-tile
constexpr int BK     = 64;    // K per B stage
constexpr int JSPLIT = 16;    // split of M across blockIdx.y

// LDS layout (bytes):
//   [0, 32768)       : A panel 64 rows x 256 K (swizzled image), staged once
//   [32768, 49152)   : B double-buffer, 2 x 8 KB
//   [49152, 51200)   : tcol panel (512 x f32)
//   [51200, 53248)   : coef panel (512 x f32)
//   [53248, 53504)   : srow panel (64 x f32)
// 53504 B -> 3 blocks/CU (160512 <= 163840) -> 12 waves/CU = 3/SIMD
constexpr int B_OFF     = 32768;
constexpr int AUX_TCOL  = 49152;
constexpr int AUX_COEF  = 51200;
constexpr int AUX_SROW  = 53248;
constexpr int LDS_BYTES = 53504;

// ---------- helpers ----------
__device__ __forceinline__ unsigned short f2bf(float f) {
    unsigned int x = __float_as_uint(f);
    x += 0x7FFFu + ((x >> 16) & 1u);          // RNE
    return (unsigned short)(x >> 16);
}

__device__ __forceinline__ void gload16(void* lds, const void* g) {
    __builtin_amdgcn_global_load_lds(
        (const __attribute__((address_space(1))) void*)g,
        (__attribute__((address_space(3))) void*)lds, 16, 0, 0);
}

// ---------- prep: cast to bf16, row |x|^2, coefs, out-init ----------
__global__ void prep_all_kernel(const float* __restrict__ X,
                                const float* __restrict__ Xt,
                                const float* __restrict__ alphas,
                                const float* __restrict__ y,
                                const float* __restrict__ b,
                                unsigned short* __restrict__ Abf,
                                unsigned short* __restrict__ Bbf,
                                float* __restrict__ srow,
                                float* __restrict__ tcol,
                                float* __restrict__ coef,
                                float* __restrict__ out,
                                int N, int M) {
    int w = threadIdx.x >> 6;         // one wave per row
    int l = threadIdx.x & 63;
    int row = blockIdx.x * 4 + w;
    if (row >= N + M) return;
    const float* src;
    unsigned short* dst;
    if (row < N) { src = X  + (size_t)row * D;       dst = Abf + (size_t)row * D; }
    else         { src = Xt + (size_t)(row - N) * D; dst = Bbf + (size_t)(row - N) * D; }
    const float4 v = reinterpret_cast<const float4*>(src)[l];
    ushort4 u;
    u.x = f2bf(v.x); u.y = f2bf(v.y); u.z = f2bf(v.z); u.w = f2bf(v.w);
    reinterpret_cast<ushort4*>(dst)[l] = u;
    float ss = v.x * v.x + v.y * v.y + v.z * v.z + v.w * v.w;
    #pragma unroll
    for (int off = 32; off >= 1; off >>= 1) ss += __shfl_xor(ss, off);
    if (l == 0) {
        float folded = -GAMMA_ * LOG2E_ * ss;
        if (row < N) { srow[row] = folded; out[row] = b[0]; }
        else {
            int r2 = row - N;
            tcol[r2] = folded;
            coef[r2] = alphas[r2] * y[r2];
        }
    }
}

// ---------- fused RBF-SVM predict: low-register high-occupancy tile ----------
// pred_i = sum_j exp2( s_i + t_j + (2*g*log2e) * <x_i, xt_j> ) * coef_j + b
// 4 waves in 2x2; wave tile 32x32 (acc = 16 AGPR only). A panel LDS-resident;
// B double-buffered, counted vmcnt(2); ~90 total regs -> 3 blocks/CU.
__launch_bounds__(256, 3)
__global__ void svm_main_kernel(const unsigned short* __restrict__ Abf,
                                const unsigned short* __restrict__ Bbf,
                                const float* __restrict__ srow,
                                const float* __restrict__ tcol,
                                const float* __restrict__ coef,
                                float* __restrict__ out,
                                int M) {
    __shared__ char L[LDS_BYTES];

    const int tid = threadIdx.x;
    const int w   = tid >> 6;          // wave 0..3
    const int l   = tid & 63;
    const int wr  = w >> 1;            // row group 0..1 (32 rows each)
    const int wc  = w & 1;             // col group 0..1 (32 cols each)
    const int hi  = l >> 4;            // 0..3
    const int lo  = l & 15;
    const int row0   = blockIdx.x * BM;
    const int jspan  = M / JSPLIT;     // 512
    const int jbase  = blockIdx.y * jspan;
    const int NS     = (jspan / BN) * (D / BK);   // 8 jt x 4 kt = 32 stages

    // ---- stage A panel (32 KB) once: linear dest, inverse-swizzled src ----
    {
        const char* Ab = (const char*)Abf + (size_t)row0 * 512;
        #pragma unroll
        for (int c = 0; c < 8; ++c) {
            int x   = c * 4096 + tid * 16;
            int row = x >> 9;                        // 512 B per row
            int src = row * 512 + ((x & 511) ^ ((row & 7) << 4));
            gload16(L + x, Ab + src);
        }
    }
    // ---- aux panels ----
    if (tid < 128)       gload16(L + AUX_TCOL + tid * 16,
                                 (const char*)(tcol + jbase) + tid * 16);
    else                 gload16(L + AUX_COEF + (tid - 128) * 16,
                                 (const char*)(coef + jbase) + (tid - 128) * 16);
    if (tid < 16)        gload16(L + AUX_SROW + tid * 16,
                                 (const char*)(srow + row0) + tid * 16);
    asm volatile("s_waitcnt vmcnt(0)" ::: "memory");
    __builtin_amdgcn_s_barrier();                    // A + aux visible

    // per-lane row constants
    float sreg[2][4];
    #pragma unroll
    for (int mi = 0; mi < 2; ++mi)
        #pragma unroll
        for (int r = 0; r < 4; ++r)
            sreg[mi][r] = *(const float*)(L + AUX_SROW
                            + (wr * 32 + mi * 16 + hi * 4 + r) * 4);

    float partial[2][4];
    #pragma unroll
    for (int mi = 0; mi < 2; ++mi)
        #pragma unroll
        for (int r = 0; r < 4; ++r) partial[mi][r] = 0.0f;

    // ---- B staging: 8 KB/stage, 2 gload16/thread, double-buffered ----
    const char* Bb = (const char*)Bbf + (size_t)jbase * 512;
    auto issueB = [&](int s) {                       // stage s = jt*4 + kt
        const int jt = s >> 2, kt = s & 3, buf = s & 1;
        #pragma unroll
        for (int c = 0; c < 2; ++c) {
            int x   = c * 4096 + tid * 16;
            int col = x >> 7;                        // 128 B per col-row
            int src = (jt * BN + col) * 512 + kt * 128
                    + ((x & 127) ^ ((col & 7) << 4));
            gload16(L + B_OFF + buf * 8192 + x, Bb + src);
        }
    };

    const float K2G = 2.0f * GAMMA_ * LOG2E_;
    f32x4 acc[2][2];

    issueB(0);   // prologue: stage 0 in flight (2 loads)

    for (int s = 0; s < NS; ++s) {
        const int kt  = s & 3;
        const int buf = s & 1;

        if (kt == 0) {
            #pragma unroll
            for (int mi = 0; mi < 2; ++mi)
                #pragma unroll
                for (int ni = 0; ni < 2; ++ni) {
                    f32x4 z = {0.f, 0.f, 0.f, 0.f};
                    acc[mi][ni] = z;
                }
        }

        // issue next stage into the other buffer; counted wait for stage s
        if (s + 1 < NS) {
            issueB(s + 1);
            asm volatile("s_waitcnt vmcnt(2)" ::: "memory");
        } else {
            asm volatile("s_waitcnt vmcnt(0)" ::: "memory");
        }
        __builtin_amdgcn_s_barrier();                // stage-s B visible

        // ---- 8 ds_read_b128 + 8 MFMA (compiler co-schedules w/ lgkmcnt) ----
        #pragma unroll
        for (int ks = 0; ks < 2; ++ks) {
            bf16x8 aa[2], bb[2];
            #pragma unroll
            for (int mi = 0; mi < 2; ++mi) {
                int row = wr * 32 + mi * 16 + lo;
                int off = row * 512
                        + ((kt * 128 + ks * 64 + hi * 16) ^ ((row & 7) << 4));
                aa[mi] = *(const bf16x8*)(L + off);
            }
            #pragma unroll
            for (int ni = 0; ni < 2; ++ni) {
                int col = wc * 32 + ni * 16 + lo;
                int off = B_OFF + buf * 8192 + col * 128
                        + ((ks * 64 + hi * 16) ^ ((col & 7) << 4));
                bb[ni] = *(const bf16x8*)(L + off);
            }
            __builtin_amdgcn_s_setprio(1);
            #pragma unroll
            for (int mi = 0; mi < 2; ++mi)
                #pragma unroll
                for (int ni = 0; ni < 2; ++ni)
                    acc[mi][ni] = __builtin_amdgcn_mfma_f32_16x16x32_bf16(
                        aa[mi], bb[ni], acc[mi][ni], 0, 0, 0);
            __builtin_amdgcn_s_setprio(0);
        }
        __builtin_amdgcn_s_barrier();                // buf reads done

        // ---- per-j-tile fused epilogue (DMA for s+1 already in flight) ----
        if (kt == 3) {
            const int jt = s >> 2;
            #pragma unroll
            for (int ni = 0; ni < 2; ++ni) {
                int cl = jt * BN + wc * 32 + ni * 16 + lo;
                float t  = *(const float*)(L + AUX_TCOL + cl * 4);
                float cf = *(const float*)(L + AUX_COEF + cl * 4);
                #pragma unroll
                for (int mi = 0; mi < 2; ++mi) {
                    #pragma unroll
                    for (int r = 0; r < 4; ++r) {
                        float arg = fmaf(acc[mi][ni][r], K2G, sreg[mi][r] + t);
                        float p = __builtin_amdgcn_exp2f(arg);
                        partial[mi][r] = fmaf(p, cf, partial[mi][r]);
                    }
                }
            }
        }
    }

    // ---- reduce across the 16 lanes of each row group, one atomic per row ----
    #pragma unroll
    for (int mi = 0; mi < 2; ++mi) {
        #pragma unroll
        for (int r = 0; r < 4; ++r) {
            float v = partial[mi][r];
            v += __shfl_xor(v, 1);
            v += __shfl_xor(v, 2);
            v += __shfl_xor(v, 4);
            v += __shfl_xor(v, 8);
            if (lo == 0) {
                int rowg = row0 + wr * 32 + mi * 16 + hi * 4 + r;
                atomicAdd(&out[rowg], v);
            }
        }
    }
}

// ---------- launcher ----------
extern "C" void kernel_launch(void* const* d_in, const int* in_sizes, int n_in,
                              void* d_out, int out_size, void* d_ws, size_t ws_size,
                              hipStream_t stream) {
    const float* X      = (const float*)d_in[0];
    const float* Xt     = (const float*)d_in[1];
    const float* alphas = (const float*)d_in[2];
    const float* y      = (const float*)d_in[3];
    const float* b      = (const float*)d_in[4];
    float* out = (float*)d_out;

    const int N = in_sizes[0] / D;   // 8192
    const int M = in_sizes[1] / D;   // 8192

    // workspace: bf16 X | bf16 Xt | srow[N] | tcol[M] | coef[M]
    char* ws = (char*)d_ws;
    unsigned short* Abf = (unsigned short*)ws;
    unsigned short* Bbf = Abf + (size_t)N * D;
    float* srow = (float*)(Bbf + (size_t)M * D);
    float* tcol = srow + N;
    float* coef = tcol + M;

    prep_all_kernel<<<(N + M) / 4, 256, 0, stream>>>(X, Xt, alphas, y, b,
                                                     Abf, Bbf, srow, tcol, coef,
                                                     out, N, M);

    dim3 grid(N / BM, JSPLIT);   // 128 x 16 = 2048 blocks, 3 resident/CU
    svm_main_kernel<<<grid, 256, 0, stream>>>(Abf, Bbf, srow, tcol, coef, out, M);
}